// Round 1
// baseline (1853.449 us; speedup 1.0000x reference)
//
#include <hip/hip_runtime.h>

#define BB 16384
#define SS 50
#define DD 256
#define HH 128
#define NB 16                 // b's per persistent block
#define GRID (BB / NB)        // 1024 blocks = 4 blocks/CU, fully resident

typedef __attribute__((ext_vector_type(8))) __bf16 bf16x8;
typedef __attribute__((ext_vector_type(4))) float f32x4;

// ws prep: W1 [256][128] fp32 -> W1^T [128][256] bf16 (B-operand: n-major, k contiguous)
__global__ __launch_bounds__(256) void prep_w1(const float* __restrict__ W1,
                                               __bf16* __restrict__ w1t) {
    int idx = blockIdx.x * 256 + threadIdx.x;   // 32768 total
    int n = idx >> 8;     // 0..127
    int k = idx & 255;    // 0..255
    w1t[n * 256 + k] = (__bf16)W1[k * HH + n];
}

// alpha_pad = exp(tanh(pad·W1 + b1)·W2 + b2): identical for every masked row of
// every b -> compute ONCE in fp32 (more accurate than the old bf16-MFMA path).
__global__ __launch_bounds__(128) void prep_pad(const float* __restrict__ pad,
                                                const float* __restrict__ W1,
                                                const float* __restrict__ b1,
                                                const float* __restrict__ W2,
                                                const float* __restrict__ b2,
                                                float* __restrict__ apad) {
    __shared__ float s2[2];
    const int h = threadIdx.x;            // 0..127
    float a = b1[h];
    for (int k = 0; k < DD; ++k) a = fmaf(pad[k], W1[k * HH + h], a);
    float v = tanhf(a) * W2[h];
    #pragma unroll
    for (int off = 1; off < 64; off <<= 1) v += __shfl_xor(v, off);
    if ((h & 63) == 0) s2[h >> 6] = v;
    __syncthreads();
    if (h == 0) apad[0] = __expf(s2[0] + s2[1] + b2[0]);
}

template <bool USE_WS>
__global__ __launch_bounds__(256, 4) void user_enc(
    const float* __restrict__ vecs,   // [B,S,D]
    const int*   __restrict__ lmask,  // [B,S]
    const float* __restrict__ pad,    // [D]
    const float* __restrict__ b1,     // [H2]
    const float* __restrict__ W2,     // [H2]
    const float* __restrict__ b2,     // [1]
    const __bf16* __restrict__ w1t,   // [H2][D] bf16 (if USE_WS)
    const float* __restrict__ W1f,    // [D][H2] fp32 (fallback)
    const float* __restrict__ apad_ws,// [1] alpha_pad (if USE_WS)
    float* __restrict__ out)          // [B,D]
{
    __shared__ float s_alpha[2][SS];
    __shared__ float s_m[2][SS];
    __shared__ __align__(16) float s_part[2][256 * 4];
    __shared__ float s_sum[2][4], s_pad2[2][4];

    const int t    = threadIdx.x;
    const int wid  = t >> 6;
    const int lane = t & 63;
    const int lo16 = lane & 15;
    const int q    = lane >> 4;
    const int r    = (wid << 4) + lo16;        // this lane's A row (s index)

    const float b2v   = b2[0];
    const float apadv = USE_WS ? apad_ws[0] : 0.0f;
    const int   bbase = blockIdx.x * NB;

    // masks for the first pair
    bool act[2];
    #pragma unroll
    for (int u = 0; u < 2; ++u)
        act[u] = (r < SS) && (lmask[(size_t)(bbase + u) * SS + r] != 0);

    for (int p = 0; p < NB / 2; ++p) {
        const int b = bbase + 2 * p;
        const float* vb0 = vecs + (size_t)b * (SS * DD);
        const float* vb1 = vb0 + SS * DD;

        // ---- A fragments for both b's. Active lanes: 16 indep 16B loads each
        //      (L2-hot thanks to last iteration's touch-prefetch). Masked lanes:
        //      zero fragments (USE_WS) -> no pad loads, no pad cvt.
        bf16x8 afr[2][8];
        #pragma unroll
        for (int u = 0; u < 2; ++u) {
            const float* vrowp = (u ? vb1 : vb0) + (size_t)r * DD;
            if constexpr (USE_WS) {
                #pragma unroll
                for (int kk = 0; kk < 8; ++kk) {
                    bf16x8 f;
                    #pragma unroll
                    for (int j = 0; j < 8; ++j) f[j] = (__bf16)0.0f;
                    afr[u][kk] = f;
                }
                if (act[u]) {
                    #pragma unroll
                    for (int kk = 0; kk < 8; ++kk) {
                        const float* src = vrowp + kk * 32 + q * 8;
                        float4 lo = *(const float4*)(src);
                        float4 hi = *(const float4*)(src + 4);
                        bf16x8 f;
                        f[0] = (__bf16)lo.x; f[1] = (__bf16)lo.y; f[2] = (__bf16)lo.z; f[3] = (__bf16)lo.w;
                        f[4] = (__bf16)hi.x; f[5] = (__bf16)hi.y; f[6] = (__bf16)hi.z; f[7] = (__bf16)hi.w;
                        afr[u][kk] = f;
                    }
                }
            } else {
                // fallback: old semantics (pad defaults through the MFMA)
                #pragma unroll
                for (int kk = 0; kk < 8; ++kk) {
                    const float* src = pad + kk * 32 + q * 8;
                    float4 lo = *(const float4*)(src);
                    float4 hi = *(const float4*)(src + 4);
                    bf16x8 f;
                    f[0] = (__bf16)lo.x; f[1] = (__bf16)lo.y; f[2] = (__bf16)lo.z; f[3] = (__bf16)lo.w;
                    f[4] = (__bf16)hi.x; f[5] = (__bf16)hi.y; f[6] = (__bf16)hi.z; f[7] = (__bf16)hi.w;
                    afr[u][kk] = f;
                }
                if (act[u]) {
                    #pragma unroll
                    for (int kk = 0; kk < 8; ++kk) {
                        const float* src = vrowp + kk * 32 + q * 8;
                        float4 lo = *(const float4*)(src);
                        float4 hi = *(const float4*)(src + 4);
                        bf16x8 f;
                        f[0] = (__bf16)lo.x; f[1] = (__bf16)lo.y; f[2] = (__bf16)lo.z; f[3] = (__bf16)lo.w;
                        f[4] = (__bf16)hi.x; f[5] = (__bf16)hi.y; f[6] = (__bf16)hi.z; f[7] = (__bf16)hi.w;
                        afr[u][kk] = f;
                    }
                }
            }
        }
        if (q == 0 && r < SS) {
            s_m[0][r] = act[0] ? 1.0f : 0.0f;
            s_m[1][r] = act[1] ? 1.0f : 0.0f;
        }

        // ---- L2 touch-prefetch of the NEXT pair's active rows: one 4B load per
        //      64B line (16 rows x 4 q-lanes x 4 touches = full 1KB row each).
        //      Issued after this pair's A-loads; drained by barrier #1's vmcnt(0),
        //      which overlaps the whole GEMM phase.
        bool actn[2] = {false, false};
        float tch[8] = {0.f, 0.f, 0.f, 0.f, 0.f, 0.f, 0.f, 0.f};
        if (p + 1 < NB / 2) {
            #pragma unroll
            for (int u = 0; u < 2; ++u) {
                actn[u] = (r < SS) && (lmask[(size_t)(b + 2 + u) * SS + r] != 0);
                if (actn[u]) {
                    const float* vn = vecs + (size_t)(b + 2 + u) * (SS * DD) + (size_t)r * DD;
                    #pragma unroll
                    for (int j = 0; j < 4; ++j)
                        tch[u * 4 + j] = vn[(q * 4 + j) * 16];
                }
            }
        }

        // ---- GEMM (8 n-tiles x 8 k-steps), each bfr shared by BOTH b's ----
        float zacc[2][4] = {{0.f,0.f,0.f,0.f},{0.f,0.f,0.f,0.f}};
        #pragma unroll
        for (int nt = 0; nt < 8; ++nt) {
            const int c = (nt << 4) + lo16;       // output column (h index)
            f32x4 acc0 = {0.f,0.f,0.f,0.f};
            f32x4 acc1 = {0.f,0.f,0.f,0.f};
            #pragma unroll
            for (int kk = 0; kk < 8; ++kk) {
                bf16x8 bfr;
                if constexpr (USE_WS) {
                    bfr = *(const bf16x8*)(w1t + c * 256 + kk * 32 + q * 8);  // L1/L2-hot 64KB
                } else {
                    #pragma unroll
                    for (int j = 0; j < 8; ++j)
                        bfr[j] = (__bf16)W1f[(kk * 32 + q * 8 + j) * HH + c];
                }
                acc0 = __builtin_amdgcn_mfma_f32_16x16x32_bf16(afr[0][kk], bfr, acc0, 0, 0, 0);
                acc1 = __builtin_amdgcn_mfma_f32_16x16x32_bf16(afr[1][kk], bfr, acc1, 0, 0, 0);
            }
            const float b1c = b1[c];
            const float w2c = W2[c];
            #pragma unroll
            for (int i = 0; i < 4; ++i) {
                {
                    float y = acc0[i] + b1c;
                    y = fminf(fmaxf(y, -15.f), 15.f);
                    float ex = __expf(2.f * y);
                    zacc[0][i] += (ex - 1.f) * __builtin_amdgcn_rcpf(ex + 1.f) * w2c;
                }
                {
                    float y = acc1[i] + b1c;
                    y = fminf(fmaxf(y, -15.f), 15.f);
                    float ex = __expf(2.f * y);
                    zacc[1][i] += (ex - 1.f) * __builtin_amdgcn_rcpf(ex + 1.f) * w2c;
                }
            }
        }

        // ---- z reduce across 16 columns; alpha numerators to LDS.
        //      Masked rows get the analytic alpha_pad (USE_WS).
        const float actf0 = act[0] ? 1.f : 0.f;
        const float actf1 = act[1] ? 1.f : 0.f;
        #pragma unroll
        for (int i = 0; i < 4; ++i) {
            float z0 = zacc[0][i], z1 = zacc[1][i];
            z0 += __shfl_xor(z0, 1); z0 += __shfl_xor(z0, 2);
            z0 += __shfl_xor(z0, 4); z0 += __shfl_xor(z0, 8);
            z1 += __shfl_xor(z1, 1); z1 += __shfl_xor(z1, 2);
            z1 += __shfl_xor(z1, 4); z1 += __shfl_xor(z1, 8);
            const int srow = (wid << 4) + (q << 2) + i;
            // mask of row srow lives in lane (q*4+i) of this wave
            const float a0 = __shfl(actf0, (q << 2) + i);
            const float a1 = __shfl(actf1, (q << 2) + i);
            if (lo16 == 0 && srow < SS) {
                if constexpr (USE_WS) {
                    s_alpha[0][srow] = (a0 != 0.f) ? __expf(z0 + b2v) : apadv;
                    s_alpha[1][srow] = (a1 != 0.f) ? __expf(z1 + b2v) : apadv;
                } else {
                    s_alpha[0][srow] = __expf(z0 + b2v);
                    s_alpha[1][srow] = __expf(z1 + b2v);
                }
            }
        }

        // keep touch loads alive (prevent DCE); barrier below drains vmcnt anyway
        asm volatile("" :: "v"(tch[0]), "v"(tch[1]), "v"(tch[2]), "v"(tch[3]),
                           "v"(tch[4]), "v"(tch[5]), "v"(tch[6]), "v"(tch[7]));
        __syncthreads();   // barrier #1

        // ---- weighted sum: coalesced L2-hot re-read of active rows; masked rows
        //      folded analytically as (sum_masked alpha) * pad ----
        #pragma unroll
        for (int u = 0; u < 2; ++u) {
            const float* vbu = u ? vb1 : vb0;
            float4 acc4 = {0.f, 0.f, 0.f, 0.f};
            float asum = 0.f, apacc = 0.f;
            for (int s = wid; s < SS; s += 4) {
                float a = s_alpha[u][s];
                asum += a;
                if (s_m[u][s] != 0.0f) {           // wave-uniform branch: skip load
                    float4 xv = *(const float4*)(vbu + s * DD + lane * 4);
                    acc4.x += a * xv.x;
                    acc4.y += a * xv.y;
                    acc4.z += a * xv.z;
                    acc4.w += a * xv.w;
                } else {
                    apacc += a;
                }
            }
            *(float4*)&s_part[u][t * 4] = acc4;
            if (lane == 0) { s_sum[u][wid] = asum; s_pad2[u][wid] = apacc; }
        }
        __syncthreads();   // barrier #2

        // ---- output: wave 0 -> b, wave 1 -> b+1 ----
        if (wid < 2) {
            const int u = wid;
            float4 p0 = *(const float4*)&s_part[u][(0 * 64 + lane) * 4];
            float4 p1 = *(const float4*)&s_part[u][(1 * 64 + lane) * 4];
            float4 p2 = *(const float4*)&s_part[u][(2 * 64 + lane) * 4];
            float4 p3 = *(const float4*)&s_part[u][(3 * 64 + lane) * 4];
            float denom = s_sum[u][0] + s_sum[u][1] + s_sum[u][2] + s_sum[u][3] + 1e-8f;
            float ptot  = s_pad2[u][0] + s_pad2[u][1] + s_pad2[u][2] + s_pad2[u][3];
            float inv = 1.0f / denom;
            float4 pd = *(const float4*)(pad + lane * 4);
            float4 o;
            o.x = (p0.x + p1.x + p2.x + p3.x + ptot * pd.x) * inv;
            o.y = (p0.y + p1.y + p2.y + p3.y + ptot * pd.y) * inv;
            o.z = (p0.z + p1.z + p2.z + p3.z + ptot * pd.z) * inv;
            o.w = (p0.w + p1.w + p2.w + p3.w + ptot * pd.w) * inv;
            *(float4*)(out + (size_t)(b + u) * DD + lane * 4) = o;
        }
        // NOTE: no third barrier needed — next iteration's s_m/s_alpha writes are
        // ordered after barrier #2 (all pass-2 reads done), and next s_part writes
        // are ordered after next barrier #1 (all output reads done).
        act[0] = actn[0];
        act[1] = actn[1];
    }
}

extern "C" void kernel_launch(void* const* d_in, const int* in_sizes, int n_in,
                              void* d_out, int out_size, void* d_ws, size_t ws_size,
                              hipStream_t stream) {
    const float* vecs  = (const float*)d_in[0];
    const int*   lmask = (const int*)d_in[1];
    const float* pad   = (const float*)d_in[2];
    const float* W1    = (const float*)d_in[3];
    const float* b1    = (const float*)d_in[4];
    const float* W2    = (const float*)d_in[5];
    const float* b2    = (const float*)d_in[6];
    float* out = (float*)d_out;

    const size_t w1t_bytes = (size_t)HH * DD * sizeof(__bf16);   // 64 KB
    if (ws_size >= w1t_bytes + 16) {
        __bf16* w1t = (__bf16*)d_ws;
        float*  apad = (float*)((char*)d_ws + w1t_bytes);
        prep_w1<<<dim3(HH * DD / 256), dim3(256), 0, stream>>>(W1, w1t);
        prep_pad<<<dim3(1), dim3(128), 0, stream>>>(pad, W1, b1, W2, b2, apad);
        user_enc<true><<<dim3(GRID), dim3(256), 0, stream>>>(vecs, lmask, pad, b1, W2, b2,
                                                             w1t, W1, apad, out);
    } else {
        user_enc<false><<<dim3(GRID), dim3(256), 0, stream>>>(vecs, lmask, pad, b1, W2, b2,
                                                              nullptr, W1, nullptr, out);
    }
}

// Round 2
// 1217.899 us; speedup vs baseline: 1.5218x; 1.5218x over previous
//
#include <hip/hip_runtime.h>

#define BB 16384
#define SS 50
#define DD 256
#define HH 128
#define NB 16                 // b's per persistent block
#define GRID (BB / NB)        // 1024 blocks

typedef __attribute__((ext_vector_type(8))) __bf16 bf16x8;
typedef __attribute__((ext_vector_type(4))) float f32x4;

// ws prep: W1 [256][128] fp32 -> W1^T [128][256] bf16 (B-operand: n-major, k contiguous)
__global__ __launch_bounds__(256) void prep_w1(const float* __restrict__ W1,
                                               __bf16* __restrict__ w1t) {
    int idx = blockIdx.x * 256 + threadIdx.x;   // 32768 total
    int n = idx >> 8;     // 0..127
    int k = idx & 255;    // 0..255
    w1t[n * 256 + k] = (__bf16)W1[k * HH + n];
}

// alpha_pad = exp(tanh(pad·W1 + b1)·W2 + b2): identical for every masked row of
// every b -> compute ONCE in fp32.
__global__ __launch_bounds__(128) void prep_pad(const float* __restrict__ pad,
                                                const float* __restrict__ W1,
                                                const float* __restrict__ b1,
                                                const float* __restrict__ W2,
                                                const float* __restrict__ b2,
                                                float* __restrict__ apad) {
    __shared__ float s2[2];
    const int h = threadIdx.x;            // 0..127
    float a = b1[h];
    for (int k = 0; k < DD; ++k) a = fmaf(pad[k], W1[k * HH + h], a);
    float v = tanhf(a) * W2[h];
    #pragma unroll
    for (int off = 1; off < 64; off <<= 1) v += __shfl_xor(v, off);
    if ((h & 63) == 0) s2[h >> 6] = v;
    __syncthreads();
    if (h == 0) apad[0] = __expf(s2[0] + s2[1] + b2[0]);
}

// Decomposition: wave w owns output columns [32w, 32w+32) -> its 16 B-fragments
// (64 VGPRs) are loaded ONCE and reused for all NB b's (zero steady-state B
// traffic). A (x rows) lives in a 32 KB XOR-swizzled LDS tile per b; A-fragments
// are transient -> no register blowup (round-1 spill lesson).
template <bool USE_WS>
__global__ __launch_bounds__(256) void user_enc(
    const float* __restrict__ vecs,   // [B,S,D]
    const int*   __restrict__ lmask,  // [B,S]
    const float* __restrict__ pad,    // [D]
    const float* __restrict__ b1,     // [H2]
    const float* __restrict__ W2,     // [H2]
    const float* __restrict__ b2,     // [1]
    const __bf16* __restrict__ w1t,   // [H2][D] bf16 (if USE_WS)
    const float* __restrict__ W1f,    // [D][H2] fp32 (fallback)
    const float* __restrict__ apad_ws,// [1] alpha_pad (if USE_WS)
    float* __restrict__ out)          // [B,D]
{
    // x tile: [64 rows][256 cols] bf16, XOR-swizzled: 16B-chunk c16 of row r is
    // stored at chunk (c16 ^ (r&7)). Breaks the 512B-row-stride bank conflict
    // on ds_read_b128 (16-way -> 2-way = free).
    __shared__ __align__(16) __bf16 s_x[64 * 256];     // 32 KB
    __shared__ float s_z[4][64];                       // per-wave z partials
    __shared__ float s_alpha[64];
    __shared__ float s_m[64];
    __shared__ __align__(16) float s_part[256 * 4];
    __shared__ float s_sum[4], s_apad[4];

    const int t    = threadIdx.x;
    const int wid  = t >> 6;
    const int lane = t & 63;
    const int lo16 = lane & 15;
    const int q    = lane >> 4;

    const float b2v   = b2[0];
    const float apadv = USE_WS ? apad_ws[0] : 0.0f;

    // this thread's two output columns (fixed for the whole kernel)
    const int c0 = wid * 32 + lo16;
    const int c1 = c0 + 16;
    const float b1c0 = b1[c0], b1c1 = b1[c1];
    const float w2c0 = W2[c0], w2c1 = W2[c1];

    // ---- B fragments: registers for the whole kernel (64 VGPRs) ----
    bf16x8 bfr0[8], bfr1[8];
    if constexpr (USE_WS) {
        #pragma unroll
        for (int kk = 0; kk < 8; ++kk) {
            bfr0[kk] = *(const bf16x8*)(w1t + (size_t)c0 * 256 + kk * 32 + q * 8);
            bfr1[kk] = *(const bf16x8*)(w1t + (size_t)c1 * 256 + kk * 32 + q * 8);
        }
    } else {
        #pragma unroll
        for (int kk = 0; kk < 8; ++kk) {
            bf16x8 f0, f1;
            #pragma unroll
            for (int j = 0; j < 8; ++j) {
                f0[j] = (__bf16)W1f[(kk * 32 + q * 8 + j) * HH + c0];
                f1[j] = (__bf16)W1f[(kk * 32 + q * 8 + j) * HH + c1];
            }
            bfr0[kk] = f0; bfr1[kk] = f1;
        }
    }

    // zero rows 50..63 once (never rewritten; keeps first-iteration GEMM clean
    // there; masked/stale rows elsewhere are sanitized by the tanh clamp and
    // their alpha is overwritten anyway)
    for (int i = t; i < 14 * 32; i += 256) {
        int r = 50 + (i >> 5);
        int c16 = i & 31;
        *(f32x4*)((char*)s_x + r * 512 + ((c16 ^ (r & 7)) << 4)) = f32x4{0.f, 0.f, 0.f, 0.f};
    }

    const int bbase = blockIdx.x * NB;
    const int sr = t >> 2;              // staging row (4 threads/row)
    const int sc = (t & 3) * 64;        // staging col start (64 cols/thread)

    for (int p = 0; p < NB; ++p) {
        const int b = bbase + p;
        const float* vb = vecs + (size_t)b * (SS * DD);

        // ---- row masks ----
        if (t < SS) s_m[t] = (lmask[(size_t)b * SS + t] != 0) ? 1.0f : 0.0f;

        // ---- stage active x rows -> swizzled bf16 LDS tile ----
        if (sr < SS) {
            const bool act = (lmask[(size_t)b * SS + sr] != 0);
            const float* src = nullptr;
            if (act)               src = vb + sr * DD + sc;
            else if constexpr (!USE_WS) src = pad + sc;   // fallback: old semantics
            if (src) {
                const int c16b = sc >> 3;        // first 16B-chunk index
                const int swz  = sr & 7;
                #pragma unroll
                for (int jj = 0; jj < 8; ++jj) {
                    float4 lo = *(const float4*)(src + jj * 8);
                    float4 hi = *(const float4*)(src + jj * 8 + 4);
                    bf16x8 f;
                    f[0] = (__bf16)lo.x; f[1] = (__bf16)lo.y; f[2] = (__bf16)lo.z; f[3] = (__bf16)lo.w;
                    f[4] = (__bf16)hi.x; f[5] = (__bf16)hi.y; f[6] = (__bf16)hi.z; f[7] = (__bf16)hi.w;
                    *(bf16x8*)((char*)s_x + sr * 512 + (((c16b + jj) ^ swz) << 4)) = f;
                }
            }
        }
        __syncthreads();   // #1: tile ready

        // ---- GEMM: 4 row-tiles x (2 col-tiles x 8 k-steps); B held in regs ----
        #pragma unroll
        for (int mt = 0; mt < 4; ++mt) {
            f32x4 acc0 = {0.f, 0.f, 0.f, 0.f};
            f32x4 acc1 = {0.f, 0.f, 0.f, 0.f};
            const int row = mt * 16 + lo16;
            const int swz = row & 7;
            #pragma unroll
            for (int kk = 0; kk < 8; ++kk) {
                const int c16 = (kk * 4 + q) ^ swz;
                bf16x8 a = *(const bf16x8*)((const char*)s_x + row * 512 + (c16 << 4));
                acc0 = __builtin_amdgcn_mfma_f32_16x16x32_bf16(a, bfr0[kk], acc0, 0, 0, 0);
                acc1 = __builtin_amdgcn_mfma_f32_16x16x32_bf16(a, bfr1[kk], acc1, 0, 0, 0);
            }
            // fused tanh + W2 dot; reduce over this wave's 32 columns
            #pragma unroll
            for (int i = 0; i < 4; ++i) {
                float y0 = acc0[i] + b1c0;
                y0 = fminf(fmaxf(y0, -15.f), 15.f);
                float e0 = __expf(2.f * y0);
                float z  = (e0 - 1.f) * __builtin_amdgcn_rcpf(e0 + 1.f) * w2c0;
                float y1 = acc1[i] + b1c1;
                y1 = fminf(fmaxf(y1, -15.f), 15.f);
                float e1 = __expf(2.f * y1);
                z += (e1 - 1.f) * __builtin_amdgcn_rcpf(e1 + 1.f) * w2c1;
                z += __shfl_xor(z, 1);
                z += __shfl_xor(z, 2);
                z += __shfl_xor(z, 4);
                z += __shfl_xor(z, 8);
                if (lo16 == 0) s_z[wid][mt * 16 + (q << 2) + i] = z;
            }
        }
        __syncthreads();   // #2: z partials ready

        // ---- alpha: combine 4 wave partials; masked rows -> analytic pad alpha ----
        if (t < SS) {
            float z4 = s_z[0][t] + s_z[1][t] + s_z[2][t] + s_z[3][t];
            float al;
            if constexpr (USE_WS)
                al = (s_m[t] != 0.f) ? __expf(z4 + b2v) : apadv;
            else
                al = __expf(z4 + b2v);
            s_alpha[t] = al;
        }
        __syncthreads();   // #3: alpha ready

        // ---- weighted sum: coalesced fp32 re-read of active rows (L2-hot);
        //      masked rows folded analytically as (sum alpha_masked) * pad ----
        {
            float4 acc4 = {0.f, 0.f, 0.f, 0.f};
            float asum = 0.f, apacc = 0.f;
            for (int s = wid; s < SS; s += 4) {
                float a = s_alpha[s];
                asum += a;
                if (s_m[s] != 0.0f) {              // wave-uniform: skip load
                    float4 xv = *(const float4*)(vb + s * DD + lane * 4);
                    acc4.x += a * xv.x;
                    acc4.y += a * xv.y;
                    acc4.z += a * xv.z;
                    acc4.w += a * xv.w;
                } else {
                    apacc += a;
                }
            }
            *(float4*)&s_part[t * 4] = acc4;
            if (lane == 0) { s_sum[wid] = asum; s_apad[wid] = apacc; }
        }
        __syncthreads();   // #4: partials ready

        if (t < 64) {
            float4 p0 = *(const float4*)&s_part[(0 * 64 + t) * 4];
            float4 p1 = *(const float4*)&s_part[(1 * 64 + t) * 4];
            float4 p2 = *(const float4*)&s_part[(2 * 64 + t) * 4];
            float4 p3 = *(const float4*)&s_part[(3 * 64 + t) * 4];
            float denom = s_sum[0] + s_sum[1] + s_sum[2] + s_sum[3] + 1e-8f;
            float ptot  = s_apad[0] + s_apad[1] + s_apad[2] + s_apad[3];
            float inv = 1.0f / denom;
            float4 pd = *(const float4*)(pad + t * 4);
            float4 o;
            o.x = (p0.x + p1.x + p2.x + p3.x + ptot * pd.x) * inv;
            o.y = (p0.y + p1.y + p2.y + p3.y + ptot * pd.y) * inv;
            o.z = (p0.z + p1.z + p2.z + p3.z + ptot * pd.z) * inv;
            o.w = (p0.w + p1.w + p2.w + p3.w + ptot * pd.w) * inv;
            *(float4*)(out + (size_t)b * DD + t * 4) = o;
        }
        // Next iteration's s_x/s_m writes are fenced by barrier #1 (all output
        // readers must arrive there first); s_part/s_sum next writes are fenced
        // by next #1..#3. No extra barrier needed.
    }
}

extern "C" void kernel_launch(void* const* d_in, const int* in_sizes, int n_in,
                              void* d_out, int out_size, void* d_ws, size_t ws_size,
                              hipStream_t stream) {
    const float* vecs  = (const float*)d_in[0];
    const int*   lmask = (const int*)d_in[1];
    const float* pad   = (const float*)d_in[2];
    const float* W1    = (const float*)d_in[3];
    const float* b1    = (const float*)d_in[4];
    const float* W2    = (const float*)d_in[5];
    const float* b2    = (const float*)d_in[6];
    float* out = (float*)d_out;

    const size_t w1t_bytes = (size_t)HH * DD * sizeof(__bf16);   // 64 KB
    if (ws_size >= w1t_bytes + 16) {
        __bf16* w1t = (__bf16*)d_ws;
        float*  apad = (float*)((char*)d_ws + w1t_bytes);
        prep_w1<<<dim3(HH * DD / 256), dim3(256), 0, stream>>>(W1, w1t);
        prep_pad<<<dim3(1), dim3(128), 0, stream>>>(pad, W1, b1, W2, b2, apad);
        user_enc<true><<<dim3(GRID), dim3(256), 0, stream>>>(vecs, lmask, pad, b1, W2, b2,
                                                             w1t, W1, apad, out);
    } else {
        user_enc<false><<<dim3(GRID), dim3(256), 0, stream>>>(vecs, lmask, pad, b1, W2, b2,
                                                              nullptr, W1, nullptr, out);
    }
}